// Round 1
// 178.902 us; speedup vs baseline: 1.0273x; 1.0273x over previous
//
#include <hip/hip_runtime.h>

// Problem constants (match reference)
#define BATCH 32
#define NDIM  1024
#define NSEGP 1024          // padded segment slots per partial (1023 real)
#define NUSE  1022          // segments used in the mean (nseg - 1)
#define BLK   256
#define G     64            // row-groups per batch (2048 blocks = 8/CU)
#define ROWS  16            // rows per block = NDIM/G
#define RB    256           // reduce block = 4 waves
#define CHUNKS 8            // segment chunks per batch in reduce (128 segs each)

// Fully aligned 16-byte vector: all global quad accesses in this version are
// provably 16B-aligned, so the compiler emits global_load_dwordx4.
typedef float f4 __attribute__((ext_vector_type(4), aligned(16)));

// ---------------------------------------------------------------------------
// Kernel 1: register-binned partial segment sums with ALIGNED quad loads.
// Block-uniform shift r = (g+1)&3 moves each row's load window down to a
// 16-float-aligned column base (rows in a block step by 64, so (i+1)&3 is
// i-invariant). Slot k of thread t accumulates segment c0+k-r; a 4KB LDS
// staging pass un-shifts before the part write, so part stays aligned and
// unshifted for kernel 2.
// ---------------------------------------------------------------------------
__global__ __launch_bounds__(BLK) void seg_partial_kernel(
        const float* __restrict__ S,     // (BATCH, NDIM, NDIM)
        float* __restrict__ part)        // (BATCH*G, 2, NSEGP)
{
    const int b  = blockIdx.x >> 6;       // / G
    const int g  = blockIdx.x & (G - 1);  // % G
    const int r  = (g + 1) & 3;           // alignment shift (block-uniform)
    const int c0 = threadIdx.x << 2;      // slot base; slot k = segment c0+k-r

    float s0 = 0.f, s1 = 0.f, s2 = 0.f, s3 = 0.f;
    float q0 = 0.f, q1 = 0.f, q2 = 0.f, q3 = 0.f;

    // Row i = g + 64m; load columns (i+1-r)+c0 .. +3 at flat i*1024 + i+1-r + c0.
    // (i+1-r) ≡ 0 mod 4 and i*1024 ≡ 0 mod 4  →  every quad is 16B-aligned.
    const float* p = S + (size_t)b * NDIM * NDIM + (size_t)g * (NDIM + 1) + 1 - r + c0;

    #pragma unroll
    for (int m = 0; m < ROWS; ++m) {
        const int i = g + (m << 6);
        if (i < NDIM - 1) {                    // uniform (false only g=63,m=15)
            const int hi = NDIM - 2 - i + r;   // valid slots: r <= c0+k <= hi
            if (c0 <= hi) {                    // coherent lane cutoff
                // Tail quad stays in the batch: start col <= 1023, so max flat
                // index is 1022*1024 + 1026 < 1024*1024.
                f4 v = __builtin_nontemporal_load((const f4*)p);
                float v0 = (c0 + 0 >= r && c0 + 0 <= hi) ? v.x : 0.f;
                float v1 = (c0 + 1 >= r && c0 + 1 <= hi) ? v.y : 0.f;
                float v2 = (c0 + 2 >= r && c0 + 2 <= hi) ? v.z : 0.f;
                float v3 = (c0 + 3 <= hi) ? v.w : 0.f;   // c0+3 >= 3 >= r always
                s0 += v0; q0 += v0 * v0;
                s1 += v1; q1 += v1 * v1;
                s2 += v2; q2 += v2 * v2;
                s3 += v3; q3 += v3 * v3;
            }
        }
        p += (size_t)64 * (NDIM + 1);          // next row handled by this block
    }

    // Un-shift by r through LDS so part holds true segment s at psum[s].
    // lds[s + r] = slot (s+r) = segment s; pad [1024..1027] covers s+r > 1023
    // (segments this block never touches -> must be written as 0).
    __shared__ float lds[NSEGP + 4];
    if (threadIdx.x < 4) lds[NSEGP + threadIdx.x] = 0.f;

    float* psum = part + (size_t)blockIdx.x * (2 * NSEGP);

    lds[c0 + 0] = s0; lds[c0 + 1] = s1; lds[c0 + 2] = s2; lds[c0 + 3] = s3;
    __syncthreads();
    f4 o;
    o.x = lds[c0 + r + 0]; o.y = lds[c0 + r + 1];
    o.z = lds[c0 + r + 2]; o.w = lds[c0 + r + 3];
    ((f4*)psum)[threadIdx.x] = o;
    __syncthreads();                           // protect pass-1 reads

    lds[c0 + 0] = q0; lds[c0 + 1] = q1; lds[c0 + 2] = q2; lds[c0 + 3] = q3;
    __syncthreads();
    o.x = lds[c0 + r + 0]; o.y = lds[c0 + r + 1];
    o.z = lds[c0 + r + 2]; o.w = lds[c0 + r + 3];
    ((f4*)(psum + NSEGP))[threadIdx.x] = o;
}

// ---------------------------------------------------------------------------
// Kernel 2: 256 blocks (32 batches x 8 chunks of 128 segments) x 256 threads.
// Thread (gs = t>>5, q = t&31) sums its quad over 8 of the 64 g-partials;
// 8KB LDS combine across gs; lanes 0..31 of wave 0 finalize; wave-reduce.
// Every CU gets a block (4 waves) instead of the old 128 single-wave blocks.
// ---------------------------------------------------------------------------
__global__ __launch_bounds__(RB) void reduce_kernel(
        const float* __restrict__ part,  // (BATCH*G, 2, NSEGP)
        float* __restrict__ cpart)       // (BATCH*CHUNKS)
{
    const int b  = blockIdx.x >> 3;
    const int c  = blockIdx.x & (CHUNKS - 1);
    const int t  = threadIdx.x;
    const int q  = t & 31;               // quad within chunk
    const int gs = t >> 5;               // g-group 0..7
    const int qi = (c << 5) + q;         // quad index within 1024 slots

    f4 sum = {0.f, 0.f, 0.f, 0.f};
    f4 sq  = {0.f, 0.f, 0.f, 0.f};
    const float* p = part + (size_t)b * G * (2 * NSEGP);
    #pragma unroll
    for (int k = 0; k < 8; ++k) {
        const int g = (gs << 3) + k;
        const f4* pg = (const f4*)(p + (size_t)g * (2 * NSEGP));
        sum += pg[qi];
        sq  += pg[(NSEGP >> 2) + qi];
    }

    __shared__ f4 lsum[8][32];
    __shared__ f4 lsq [8][32];
    lsum[gs][q] = sum;
    lsq [gs][q] = sq;
    __syncthreads();

    if (t < 64) {                        // wave 0 only
        float acc = 0.f;
        if (t < 32) {
            f4 S = {0.f, 0.f, 0.f, 0.f};
            f4 Q = {0.f, 0.f, 0.f, 0.f};
            #pragma unroll
            for (int k = 0; k < 8; ++k) { S += lsum[k][t]; Q += lsq[k][t]; }
            #pragma unroll
            for (int rr = 0; rr < 4; ++rr) {
                const int s = (c << 7) + (t << 2) + rr;
                if (s < NUSE) {
                    float cnt  = (float)(NDIM - 1 - s);
                    float mean = S[rr] / cnt;
                    float var  = (Q[rr] - cnt * mean * mean) / (cnt - 1.0f);
                    acc += sqrtf(fmaxf(var, 0.0f)) * cnt * 0.05f;  // * cnt / 20
                }
            }
        }
        #pragma unroll
        for (int off = 32; off > 0; off >>= 1)
            acc += __shfl_down(acc, off, 64);
        if (t == 0) cpart[blockIdx.x] = acc;
    }
}

// ---------------------------------------------------------------------------
// Kernel 3: fold the 256 chunk partials -> scalar grand mean.
// ---------------------------------------------------------------------------
__global__ void final_kernel(const float* __restrict__ cpart,
                             float* __restrict__ out)
{
    float v = 0.f;
    #pragma unroll
    for (int k = 0; k < 4; ++k)
        v += cpart[threadIdx.x + (k << 6)];
    #pragma unroll
    for (int off = 32; off > 0; off >>= 1)
        v += __shfl_down(v, off, 64);
    if (threadIdx.x == 0)
        out[0] = v / (float)(BATCH * NUSE);
}

// ---------------------------------------------------------------------------
extern "C" void kernel_launch(void* const* d_in, const int* in_sizes, int n_in,
                              void* d_out, int out_size, void* d_ws, size_t ws_size,
                              hipStream_t stream) {
    const float* S = (const float*)d_in[0];
    float* out = (float*)d_out;

    float* part  = (float*)d_ws;                         // BATCH*G*2*NSEGP floats (16.8 MB)
    float* cpart = part + (size_t)BATCH * G * 2 * NSEGP; // 256 floats

    seg_partial_kernel<<<BATCH * G, BLK, 0, stream>>>(S, part);
    reduce_kernel<<<BATCH * CHUNKS, RB, 0, stream>>>(part, cpart);
    final_kernel<<<1, 64, 0, stream>>>(cpart, out);
}